// Round 22
// baseline (612.157 us; speedup 1.0000x reference)
//
#include <hip/hip_runtime.h>
#include <cstdint>

typedef float fx4 __attribute__((ext_vector_type(4)));
typedef short sx8 __attribute__((ext_vector_type(8)));
typedef short sx4 __attribute__((ext_vector_type(4)));

#define NSTATE 16
#define SEQ_LEN 2048
#define NBATCH 32
#define MROWS 65536           // NBATCH*SEQ_LEN
#define KDIM 1024
#define N1 1072
#define N1PAD 1152            // 9 packed 128-col panels
#define BK 32
#define NSTEP (KDIM / BK)     // 32 K-tiles
#define TILE_SHORTS 4096      // packed 128x32 bf16 tile (8KB)
#define TSTRIDE (NSTEP * TILE_SHORTS)   // shorts per 128-row/col panel
#define RING 4
#define SLOT_SHORTS 8192      // 256x32 per matrix per ring slot

__device__ __forceinline__ short f2bf(float f) {
  unsigned u = __float_as_uint(f);
  u += 0x7FFFu + ((u >> 16) & 1u);   // round-to-nearest-even
  return (short)(u >> 16);
}

// A&S 7.1.26 erf, |eps|<=1.5e-7, branchless. gelu(x)=0.5x(1+erf(x/sqrt2))
__device__ __forceinline__ float gelu_exact(float x) {
  float ax = fabsf(x) * 0.70710678118654752f;
  float t = __builtin_amdgcn_rcpf(fmaf(0.3275911f, ax, 1.0f));
  float p = fmaf(1.061405429f, t, -1.453152027f);
  p = fmaf(p, t, 1.421413741f);
  p = fmaf(p, t, -0.284496736f);
  p = fmaf(p, t, 0.254829592f);
  p = p * t;
  float e = __expf(-ax * ax);
  float erfv = fmaf(-p, e, 1.0f);
  erfv = copysignf(erfv, x);
  return 0.5f * x * (1.0f + erfv);
}

#define GLOAD_LDS16(gp, lp)                                                          \
  __builtin_amdgcn_global_load_lds(                                                  \
      (const __attribute__((address_space(1))) unsigned int*)(gp),                   \
      (__attribute__((address_space(3))) unsigned int*)(lp), 16, 0, 0)

#define SBAR() do { __builtin_amdgcn_s_barrier(); asm volatile("" ::: "memory"); } while (0)

// ------- fused convert+BCD: x fp32 -> bf16 packed; partial (B,C,delta) via split-K atomics -------
// Block b: panel p = b>>3, k-slab kq = b&7 (k-tiles kq*4..+3 = cols kq*128..+128).
// Phase 1: build rotated image of 4 tiles in LDS; stage W panel-8 slab (48 cols x 128 k).
// Phase 2a: dump tiles as linear memcpy (R21 proven).
// Phase 2b: mini-GEMM x_chunk(128x128) @ W_chunk(128x48) -> atomicAdd into Braw/Craw/Draw.
#define CT_STRIDE (TILE_SHORTS + 16)
__global__ __launch_bounds__(256) void convert_pack_x(
    const float* __restrict__ x, const short* __restrict__ Wt1p,
    short* __restrict__ xbp, float* __restrict__ Braw,
    float* __restrict__ Craw, float* __restrict__ Draw) {
  __shared__ short tbuf[4 * CT_STRIDE];
  __shared__ short wbuf[4 * 2048];
  const int t = threadIdx.x;             // 256
  const int p = blockIdx.x >> 3;         // panel 0..511
  const int kq = blockIdx.x & 7;         // k-slab
  const int l32 = t & 31;
  const int kt_local = l32 >> 3;
  const int q = (l32 & 7) >> 1;
  const int eo = (l32 & 1) * 4;
  const float* xb = x + ((long)p * 128) * KDIM + kq * 128 + l32 * 4;

  // stage W slab: panel 8, tiles kq*4..+3, rows 0..63 (rows 48..63 are zero-padded)
  const short* Wb = Wt1p + (long)8 * TSTRIDE + (long)(kq * 4) * TILE_SHORTS;
#pragma unroll
  for (int c = 0; c < 4; ++c)
    GLOAD_LDS16(Wb + (long)c * TILE_SHORTS + t * 8, wbuf + c * 2048 + t * 8);

#pragma unroll 4
  for (int i = 0; i < 16; ++i) {
    const int r = i * 8 + (t >> 5);
    fx4 v = *(const fx4*)(xb + (long)r * KDIM);
    sx4 o;
    o[0] = f2bf(v[0]); o[1] = f2bf(v[1]); o[2] = f2bf(v[2]); o[3] = f2bf(v[3]);
    const int phys = (q + (r >> 1)) & 3;
    *(sx4*)(tbuf + kt_local * CT_STRIDE + r * 32 + phys * 8 + eo) = o;
  }
  __syncthreads();   // drains vmcnt (wbuf) + lgkmcnt (tbuf)

  const int w = t >> 6, l = t & 63;
  // phase 2a: dump tile w as linear memcpy
  {
    short* dst = xbp + (long)p * TSTRIDE + (long)(kq * 4 + w) * TILE_SHORTS;
    const short* src = tbuf + w * CT_STRIDE;
#pragma unroll
    for (int i = 0; i < 8; ++i)
      *(sx8*)(dst + i * 512 + l * 8) = *(const sx8*)(src + i * 512 + l * 8);
  }

  // phase 2b: mini-GEMM. wave w owns rows w*32..+31; 2x3 frags; K=128 over 4 tiles.
  const int l15 = l & 15, ks = l >> 4;
  const int rslot = ((ks + (l15 >> 1)) & 3) * 8;
  fx4 acc[2][3];
#pragma unroll
  for (int i = 0; i < 2; i++)
#pragma unroll
    for (int j = 0; j < 3; j++) acc[i][j] = fx4{0.f, 0.f, 0.f, 0.f};
#pragma unroll
  for (int kt = 0; kt < 4; ++kt) {
    const short* sa = tbuf + kt * CT_STRIDE;
    const short* sb = wbuf + kt * 2048;
    sx8 af[2], bf[3];
#pragma unroll
    for (int mi = 0; mi < 2; mi++) af[mi] = *(const sx8*)(sa + (w * 32 + mi * 16 + l15) * 32 + rslot);
#pragma unroll
    for (int j = 0; j < 3; j++) bf[j] = *(const sx8*)(sb + (j * 16 + l15) * 32 + rslot);
#pragma unroll
    for (int mi = 0; mi < 2; mi++)
#pragma unroll
      for (int j = 0; j < 3; j++)
        acc[mi][j] = __builtin_amdgcn_mfma_f32_16x16x32_bf16(af[mi], bf[j], acc[mi][j], 0, 0, 0);
  }
  const long mbase = (long)p * 128 + w * 32;
#pragma unroll
  for (int mi = 0; mi < 2; mi++) {
#pragma unroll
    for (int r = 0; r < 4; r++) {
      long m = mbase + mi * 16 + (l >> 4) * 4 + r;
      atomicAdd(&Braw[m * NSTATE + l15], acc[mi][0][r]);
      atomicAdd(&Craw[m * NSTATE + l15], acc[mi][1][r]);
      atomicAdd(&Draw[m * NSTATE + l15], acc[mi][2][r]);
    }
  }
}

// ------- transpose weights -> packed [nt][kt][128][32] bf16 (zero-pad rows), rotated -------
__global__ void transpose_w_kernel(const float* __restrict__ src, short* __restrict__ dst,
                                   int src_cols, int col_off, int valid_rows) {
  __shared__ float t[32][33];
  int j0 = blockIdx.x * 32;
  int k0 = blockIdx.y * 32;
  int c = threadIdx.x & 31;
  int r = threadIdx.x >> 5;  // 0..7
#pragma unroll
  for (int i = 0; i < 4; i++) {
    int k = k0 + r + i * 8;
    int j = j0 + c;
    float v = (j < valid_rows) ? src[(long)k * src_cols + col_off + j] : 0.f;
    t[r + i * 8][c] = v;
  }
  __syncthreads();
#pragma unroll
  for (int i = 0; i < 4; i++) {
    int n = j0 + r + i * 8;
    int k = k0 + c;
    int rr = n & 127;
    long addr = ((long)(n >> 7) * NSTEP + (k >> 5)) * TILE_SHORTS + rr * 32
              + ((((k >> 3) & 3) + ((rr >> 1) & 3)) & 3) * 8 + (k & 7);
    dst[addr] = f2bf(t[c][r + i * 8]);
  }
}

// ---- 256x256 mainloop: 1024 thr / 16 waves, ring-4, SINGLE barrier/step, stage-first ----
// setprio removed (m190: hurts pre-8-phase GEMM). Compiler emits fine-grained counted
// lgkmcnt per dependent MFMA (m97/m141 evidence).
__device__ __forceinline__ void gemm_mainloop256(const short* __restrict__ Abase,
                                                 const short* __restrict__ Bbase,
                                                 short* lds, fx4 acc[4][4]) {
  const int tid = threadIdx.x;
  const int lane = tid & 63;
  const int wave = tid >> 6;                 // 0..15
  const int wm = wave >> 2, wn = wave & 3;   // 4x4 grid; wave output 64x64
  const int l15 = lane & 15, ks = lane >> 4;

#pragma unroll
  for (int i = 0; i < 4; i++)
#pragma unroll
    for (int j = 0; j < 4; j++) acc[i][j] = fx4{0.f, 0.f, 0.f, 0.f};

  short* AshR = lds;
  short* BshR = lds + RING * SLOT_SHORTS;
  const short* Asrc = Abase + (long)(tid >> 9) * TSTRIDE + (tid & 511) * 8;
  const short* Bsrc = Bbase + (long)(tid >> 9) * TSTRIDE + (tid & 511) * 8;
  const int dst = tid * 8;

  const int rslot = ((ks + (l15 >> 1)) & 3) * 8;
  const int aoff = (wm >> 1) * TILE_SHORTS + ((wm & 1) * 64 + l15) * 32 + rslot;
  const int boff = (wn >> 1) * TILE_SHORTS + ((wn & 1) * 64 + l15) * 32 + rslot;

  // prologue: stage steps 0..2 into slots 0..2
#pragma unroll
  for (int s = 0; s < RING - 1; s++) {
    GLOAD_LDS16(Asrc + (long)s * TILE_SHORTS, AshR + s * SLOT_SHORTS + dst);
    GLOAD_LDS16(Bsrc + (long)s * TILE_SHORTS, BshR + s * SLOT_SHORTS + dst);
  }

  for (int s = 0; s < NSTEP; ++s) {
    const int rem = NSTEP - 1 - s;
    if (rem >= 2)      asm volatile("s_waitcnt vmcnt(4)" ::: "memory");
    else if (rem == 1) asm volatile("s_waitcnt vmcnt(2)" ::: "memory");
    else               asm volatile("s_waitcnt vmcnt(0)" ::: "memory");
    SBAR();

    if (s + 3 < NSTEP) {
      const int sl = (s + 3) & (RING - 1);
      GLOAD_LDS16(Asrc + (long)(s + 3) * TILE_SHORTS, AshR + sl * SLOT_SHORTS + dst);
      GLOAD_LDS16(Bsrc + (long)(s + 3) * TILE_SHORTS, BshR + sl * SLOT_SHORTS + dst);
    }

    const short* sa = AshR + (s & (RING - 1)) * SLOT_SHORTS + aoff;
    const short* sb = BshR + (s & (RING - 1)) * SLOT_SHORTS + boff;
    sx8 af[4], bfr[4];
#pragma unroll
    for (int i = 0; i < 4; i++) af[i] = *(const sx8*)(sa + i * 512);
#pragma unroll
    for (int j = 0; j < 4; j++) bfr[j] = *(const sx8*)(sb + j * 512);

#pragma unroll
    for (int i = 0; i < 4; i++)
#pragma unroll
      for (int j = 0; j < 4; j++)
        acc[i][j] = __builtin_amdgcn_mfma_f32_16x16x32_bf16(af[i], bfr[j], acc[i][j], 0, 0, 0);
  }
}

// ---------------- GEMM1: g = gelu(x @ W_in[:,1024:2048] + b), packed output ---------------
__global__ __launch_bounds__(1024, 1) void gemm1_kernel(
    const short* __restrict__ xbp, const short* __restrict__ Wt1p,
    const float* __restrict__ b_in, short* __restrict__ g) {
  extern __shared__ short lds[];
  const int bid = blockIdx.x;                 // 0..1023
  const int wgid = (bid & 7) * 128 + (bid >> 3);
  const int nt = wgid & 3;
  const int mt = wgid >> 2;                   // 0..255
  fx4 acc[4][4];
  gemm_mainloop256(xbp + (long)(mt * 2) * TSTRIDE,
                   Wt1p + (long)(nt * 2) * TSTRIDE, lds, acc);

  const int lane = threadIdx.x & 63;
  const int wave = threadIdx.x >> 6;
  const int wm = wave >> 2, wn = wave & 3;
  const int m0 = mt * 256;
  const int n0 = nt * 256;

#pragma unroll
  for (int ni = 0; ni < 4; ni++) {
    int n = n0 + wn * 64 + ni * 16 + (lane & 15);
    float bias = b_in[1024 + n];
#pragma unroll
    for (int mi = 0; mi < 4; mi++) {
#pragma unroll
      for (int r = 0; r < 4; r++) {
        int m = m0 + wm * 64 + mi * 16 + (lane >> 4) * 4 + r;
        float v = acc[mi][ni][r] + bias;
        int rr = m & 127;
        long addr = ((long)(m >> 7) * NSTEP + (n >> 5)) * TILE_SHORTS + rr * 32
                  + ((((n >> 3) & 3) + ((rr >> 1) & 3)) & 3) * 8 + (n & 7);
        g[addr] = f2bf(gelu_exact(v));
      }
    }
  }
}

// ---- segmented selective scan + fused transforms + channel-reduce: 1 block/batch ----
__global__ void scan_kernel(const float* __restrict__ Braw, const float* __restrict__ Craw,
                            const float* __restrict__ Draw, const float* __restrict__ b_in,
                            const float* __restrict__ A_log, float* __restrict__ y) {
  __shared__ float Ash[16][17], Bsh[16][17];
  const int b = blockIdx.x;
  const int tid = threadIdx.x;
  const int seg = tid >> 4, ch = tid & 15;
  const long base = ((long)b * SEQ_LEN + seg * 128) * NSTATE + ch;
  const float* pB = Braw + base;
  const float* pC = Craw + base;
  const float* pD = Draw + base;
  const float biasB = b_in[2048 + ch];
  const float biasC = b_in[2064 + ch];
  const float biasD = b_in[2080 + ch];
  const float Ac = -expf(A_log[ch]);

  // pass 1: segment composition
  float A = 1.f, Bc = 0.f;
  for (int i0 = 0; i0 < 128; i0 += 8) {
    float av[8], bv[8];
#pragma unroll
    for (int u = 0; u < 8; u++) {
      float d = pD[(i0 + u) * NSTATE] + biasD;
      float dlt = (d > 20.f) ? d : log1pf(expf(d));
      av[u] = expf(Ac * dlt);
      bv[u] = pB[(i0 + u) * NSTATE] + biasB;
    }
#pragma unroll
    for (int u = 0; u < 8; u++) { Bc = fmaf(av[u], Bc, bv[u]); A *= av[u]; }
  }
  Ash[seg][ch] = A; Bsh[seg][ch] = Bc;
  __syncthreads();

  // exclusive prefix over segments, per channel
  if (tid < 16) {
    float s = 0.f;
    for (int sg = 0; sg < 16; ++sg) {
      float nxt = fmaf(Ash[sg][tid], s, Bsh[sg][tid]);
      Bsh[sg][tid] = s;          // state ENTERING segment sg
      s = nxt;
    }
  }
  __syncthreads();

  // pass 2: apply + 16-lane reduce -> y
  float s = Bsh[seg][ch];
  float* py = y + (long)b * SEQ_LEN + seg * 128;
  for (int i0 = 0; i0 < 128; i0 += 8) {
    float av[8], bv[8], cv[8];
#pragma unroll
    for (int u = 0; u < 8; u++) {
      float d = pD[(i0 + u) * NSTATE] + biasD;
      float dlt = (d > 20.f) ? d : log1pf(expf(d));
      av[u] = expf(Ac * dlt);
      bv[u] = pB[(i0 + u) * NSTATE] + biasB;
      cv[u] = pC[(i0 + u) * NSTATE] + biasC;
    }
#pragma unroll
    for (int u = 0; u < 8; u++) {
      s = fmaf(av[u], s, bv[u]);
      float p = s * cv[u];
      p += __shfl_xor(p, 1);
      p += __shfl_xor(p, 2);
      p += __shfl_xor(p, 4);
      p += __shfl_xor(p, 8);
      if (ch == 0) py[i0 + u] = p;
    }
  }
}

// ---------------- GEMM2: out = (y ⊙row g) @ W_out + b_out ----------------
__global__ __launch_bounds__(1024, 1) void gemm2_kernel(
    const short* __restrict__ g, const short* __restrict__ Wt2p,
    const float* __restrict__ y, const float* __restrict__ b_out,
    float* __restrict__ out) {
  extern __shared__ short lds[];
  const int bid = blockIdx.x;                 // 0..1023
  const int wgid = (bid & 7) * 128 + (bid >> 3);
  const int nt = wgid & 3;
  const int mt = wgid >> 2;                   // 0..255
  fx4 acc[4][4];
  gemm_mainloop256(g + (long)(mt * 2) * TSTRIDE,
                   Wt2p + (long)(nt * 2) * TSTRIDE, lds, acc);

  const int lane = threadIdx.x & 63;
  const int wave = threadIdx.x >> 6;
  const int wm = wave >> 2, wn = wave & 3;
  const int m0 = mt * 256;
  const int n0 = nt * 256;

#pragma unroll
  for (int mi = 0; mi < 4; mi++) {
#pragma unroll
    for (int r = 0; r < 4; r++) {
      int m = m0 + wm * 64 + mi * 16 + (lane >> 4) * 4 + r;
      float ym = y[m];
#pragma unroll
      for (int ni = 0; ni < 4; ni++) {
        int n = n0 + wn * 64 + ni * 16 + (lane & 15);
        out[(long)m * 1024 + n] = fmaf(ym, acc[mi][ni][r], b_out[n]);
      }
    }
  }
}

extern "C" void kernel_launch(void* const* d_in, const int* in_sizes, int n_in,
                              void* d_out, int out_size, void* d_ws, size_t ws_size,
                              hipStream_t stream) {
  const float* x     = (const float*)d_in[0];
  const float* W_in  = (const float*)d_in[1];
  const float* b_in  = (const float*)d_in[2];
  const float* A_log = (const float*)d_in[3];
  const float* W_out = (const float*)d_in[4];
  const float* b_out = (const float*)d_in[5];
  float* out = (float*)d_out;

  char* ws = (char*)d_ws;
  short* xbp = (short*)ws;  ws += (size_t)MROWS * KDIM * 2;      // 134.2 MB packed
  short* g   = (short*)ws;  ws += (size_t)MROWS * KDIM * 2;      // 134.2 MB packed
  short* Wt1p = (short*)ws; ws += (size_t)N1PAD * KDIM * 2;      // 2.36 MB packed
  short* Wt2p = (short*)ws; ws += (size_t)KDIM * KDIM * 2;       // 2.10 MB packed
  float* Braw = (float*)ws; ws += (size_t)MROWS * NSTATE * 4;    // 4.19 MB
  float* Craw = (float*)ws; ws += (size_t)MROWS * NSTATE * 4;
  float* Draw = (float*)ws; ws += (size_t)MROWS * NSTATE * 4;
  float* y  = (float*)ws;  ws += (size_t)MROWS * 4;

  const int ldsBytes = 2 * RING * SLOT_SHORTS * 2;   // 128 KB

  hipMemsetAsync(Braw, 0, (size_t)3 * MROWS * NSTATE * 4, stream);  // re-zeroed every replay
  transpose_w_kernel<<<dim3(N1PAD / 32, 32), 256, 0, stream>>>(W_in, Wt1p, 2096, 1024, N1);
  transpose_w_kernel<<<dim3(32, 32), 256, 0, stream>>>(W_out, Wt2p, 1024, 0, 1024);
  convert_pack_x<<<4096, 256, 0, stream>>>(x, Wt1p, xbp, Braw, Craw, Draw);
  scan_kernel<<<NBATCH, 256, 0, stream>>>(Braw, Craw, Draw, b_in, A_log, y);
  gemm1_kernel<<<1024, 1024, ldsBytes, stream>>>(xbp, Wt1p, b_in, g);
  gemm2_kernel<<<1024, 1024, ldsBytes, stream>>>(g, Wt2p, y, b_out, out);
}

// Round 23
// 472.404 us; speedup vs baseline: 1.2958x; 1.2958x over previous
//
#include <hip/hip_runtime.h>
#include <cstdint>

typedef float fx4 __attribute__((ext_vector_type(4)));
typedef short sx8 __attribute__((ext_vector_type(8)));
typedef short sx4 __attribute__((ext_vector_type(4)));

#define NSTATE 16
#define SEQ_LEN 2048
#define NBATCH 32
#define MROWS 65536           // NBATCH*SEQ_LEN
#define KDIM 1024
#define N1 1072
#define N1PAD 1152            // 9 packed 128-col panels
#define BK 32
#define NSTEP (KDIM / BK)     // 32 K-tiles
#define TILE_SHORTS 4096      // packed 128x32 bf16 tile (8KB)
#define TSTRIDE (NSTEP * TILE_SHORTS)   // shorts per 128-row/col panel
#define RING 4
#define SLOT_SHORTS 8192      // 256x32 per matrix per ring slot

__device__ __forceinline__ short f2bf(float f) {
  unsigned u = __float_as_uint(f);
  u += 0x7FFFu + ((u >> 16) & 1u);   // round-to-nearest-even
  return (short)(u >> 16);
}

// A&S 7.1.26 erf, |eps|<=1.5e-7, branchless. gelu(x)=0.5x(1+erf(x/sqrt2))
__device__ __forceinline__ float gelu_exact(float x) {
  float ax = fabsf(x) * 0.70710678118654752f;
  float t = __builtin_amdgcn_rcpf(fmaf(0.3275911f, ax, 1.0f));
  float p = fmaf(1.061405429f, t, -1.453152027f);
  p = fmaf(p, t, 1.421413741f);
  p = fmaf(p, t, -0.284496736f);
  p = fmaf(p, t, 0.254829592f);
  p = p * t;
  float e = __expf(-ax * ax);
  float erfv = fmaf(-p, e, 1.0f);
  erfv = copysignf(erfv, x);
  return 0.5f * x * (1.0f + erfv);
}

#define GLOAD_LDS16(gp, lp)                                                          \
  __builtin_amdgcn_global_load_lds(                                                  \
      (const __attribute__((address_space(1))) unsigned int*)(gp),                   \
      (__attribute__((address_space(3))) unsigned int*)(lp), 16, 0, 0)

#define SBAR() do { __builtin_amdgcn_s_barrier(); asm volatile("" ::: "memory"); } while (0)

// ------- convert x fp32 -> bf16 packed [mt][kt][128][32], LDS-bounced coalesced writes -------
#define CT_STRIDE (TILE_SHORTS + 16)
__global__ void convert_pack_x(const float* __restrict__ x, short* __restrict__ xbp) {
  __shared__ short tbuf[4 * CT_STRIDE];
  const int t = threadIdx.x;             // 256
  const int p = blockIdx.x >> 3;         // panel 0..511
  const int kq = blockIdx.x & 7;         // k-slab
  const int l32 = t & 31;
  const int kt_local = l32 >> 3;         // 0..3
  const int q = (l32 & 7) >> 1;          // logical 8-group within tile
  const int eo = (l32 & 1) * 4;
  const float* xb = x + ((long)p * 128) * KDIM + kq * 128 + l32 * 4;

#pragma unroll 4
  for (int i = 0; i < 16; ++i) {
    const int r = i * 8 + (t >> 5);
    fx4 v = *(const fx4*)(xb + (long)r * KDIM);
    sx4 o;
    o[0] = f2bf(v[0]); o[1] = f2bf(v[1]); o[2] = f2bf(v[2]); o[3] = f2bf(v[3]);
    const int phys = (q + (r >> 1)) & 3;
    *(sx4*)(tbuf + kt_local * CT_STRIDE + r * 32 + phys * 8 + eo) = o;
  }
  __syncthreads();

  const int w = t >> 6, l = t & 63;
  short* dst = xbp + (long)p * TSTRIDE + (long)(kq * 4 + w) * TILE_SHORTS;
  const short* src = tbuf + w * CT_STRIDE;
#pragma unroll
  for (int i = 0; i < 8; ++i)
    *(sx8*)(dst + i * 512 + l * 8) = *(const sx8*)(src + i * 512 + l * 8);
}

// ------- transpose weights -> packed [nt][kt][128][32] bf16 (zero-pad rows), rotated -------
__global__ void transpose_w_kernel(const float* __restrict__ src, short* __restrict__ dst,
                                   int src_cols, int col_off, int valid_rows) {
  __shared__ float t[32][33];
  int j0 = blockIdx.x * 32;
  int k0 = blockIdx.y * 32;
  int c = threadIdx.x & 31;
  int r = threadIdx.x >> 5;  // 0..7
#pragma unroll
  for (int i = 0; i < 4; i++) {
    int k = k0 + r + i * 8;
    int j = j0 + c;
    float v = (j < valid_rows) ? src[(long)k * src_cols + col_off + j] : 0.f;
    t[r + i * 8][c] = v;
  }
  __syncthreads();
#pragma unroll
  for (int i = 0; i < 4; i++) {
    int n = j0 + r + i * 8;
    int k = k0 + c;
    int rr = n & 127;
    long addr = ((long)(n >> 7) * NSTEP + (k >> 5)) * TILE_SHORTS + rr * 32
              + ((((k >> 3) & 3) + ((rr >> 1) & 3)) & 3) * 8 + (k & 7);
    dst[addr] = f2bf(t[c][r + i * 8]);
  }
}

// ---- 256x256 mainloop: 1024 thr / 16 waves, ring-4, SINGLE barrier/step, stage-first ----
__device__ __forceinline__ void gemm_mainloop256(const short* __restrict__ Abase,
                                                 const short* __restrict__ Bbase,
                                                 short* lds, fx4 acc[4][4]) {
  const int tid = threadIdx.x;
  const int lane = tid & 63;
  const int wave = tid >> 6;                 // 0..15
  const int wm = wave >> 2, wn = wave & 3;   // 4x4 grid; wave output 64x64
  const int l15 = lane & 15, ks = lane >> 4;

#pragma unroll
  for (int i = 0; i < 4; i++)
#pragma unroll
    for (int j = 0; j < 4; j++) acc[i][j] = fx4{0.f, 0.f, 0.f, 0.f};

  short* AshR = lds;
  short* BshR = lds + RING * SLOT_SHORTS;
  const short* Asrc = Abase + (long)(tid >> 9) * TSTRIDE + (tid & 511) * 8;
  const short* Bsrc = Bbase + (long)(tid >> 9) * TSTRIDE + (tid & 511) * 8;
  const int dst = tid * 8;

  const int rslot = ((ks + (l15 >> 1)) & 3) * 8;
  const int aoff = (wm >> 1) * TILE_SHORTS + ((wm & 1) * 64 + l15) * 32 + rslot;
  const int boff = (wn >> 1) * TILE_SHORTS + ((wn & 1) * 64 + l15) * 32 + rslot;

  // prologue: stage steps 0..2 into slots 0..2
#pragma unroll
  for (int s = 0; s < RING - 1; s++) {
    GLOAD_LDS16(Asrc + (long)s * TILE_SHORTS, AshR + s * SLOT_SHORTS + dst);
    GLOAD_LDS16(Bsrc + (long)s * TILE_SHORTS, BshR + s * SLOT_SHORTS + dst);
  }

  for (int s = 0; s < NSTEP; ++s) {
    const int rem = NSTEP - 1 - s;
    if (rem >= 2)      asm volatile("s_waitcnt vmcnt(4)" ::: "memory");
    else if (rem == 1) asm volatile("s_waitcnt vmcnt(2)" ::: "memory");
    else               asm volatile("s_waitcnt vmcnt(0)" ::: "memory");
    SBAR();

    if (s + 3 < NSTEP) {
      const int sl = (s + 3) & (RING - 1);
      GLOAD_LDS16(Asrc + (long)(s + 3) * TILE_SHORTS, AshR + sl * SLOT_SHORTS + dst);
      GLOAD_LDS16(Bsrc + (long)(s + 3) * TILE_SHORTS, BshR + sl * SLOT_SHORTS + dst);
    }

    const short* sa = AshR + (s & (RING - 1)) * SLOT_SHORTS + aoff;
    const short* sb = BshR + (s & (RING - 1)) * SLOT_SHORTS + boff;
    sx8 af[4], bfr[4];
#pragma unroll
    for (int i = 0; i < 4; i++) af[i] = *(const sx8*)(sa + i * 512);
#pragma unroll
    for (int j = 0; j < 4; j++) bfr[j] = *(const sx8*)(sb + j * 512);

    __builtin_amdgcn_s_setprio(1);
#pragma unroll
    for (int i = 0; i < 4; i++)
#pragma unroll
      for (int j = 0; j < 4; j++)
        acc[i][j] = __builtin_amdgcn_mfma_f32_16x16x32_bf16(af[i], bfr[j], acc[i][j], 0, 0, 0);
    __builtin_amdgcn_s_setprio(0);
  }
}

// ---------------- GEMM1: g = gelu(x @ W_in[:,1024:2048] + b), packed output ---------------
__global__ __launch_bounds__(1024, 1) void gemm1_kernel(
    const short* __restrict__ xbp, const short* __restrict__ Wt1p,
    const float* __restrict__ b_in, short* __restrict__ g) {
  extern __shared__ short lds[];
  const int bid = blockIdx.x;                 // 0..1023
  const int wgid = (bid & 7) * 128 + (bid >> 3);
  const int nt = wgid & 3;
  const int mt = wgid >> 2;                   // 0..255
  fx4 acc[4][4];
  gemm_mainloop256(xbp + (long)(mt * 2) * TSTRIDE,
                   Wt1p + (long)(nt * 2) * TSTRIDE, lds, acc);

  const int lane = threadIdx.x & 63;
  const int wave = threadIdx.x >> 6;
  const int wm = wave >> 2, wn = wave & 3;
  const int m0 = mt * 256;
  const int n0 = nt * 256;

#pragma unroll
  for (int ni = 0; ni < 4; ni++) {
    int n = n0 + wn * 64 + ni * 16 + (lane & 15);
    float bias = b_in[1024 + n];
#pragma unroll
    for (int mi = 0; mi < 4; mi++) {
#pragma unroll
      for (int r = 0; r < 4; r++) {
        int m = m0 + wm * 64 + mi * 16 + (lane >> 4) * 4 + r;
        float v = acc[mi][ni][r] + bias;
        int rr = m & 127;
        long addr = ((long)(m >> 7) * NSTEP + (n >> 5)) * TILE_SHORTS + rr * 32
                  + ((((n >> 3) & 3) + ((rr >> 1) & 3)) & 3) * 8 + (n & 7);
        g[addr] = f2bf(gelu_exact(v));
      }
    }
  }
}

// ---- GEMM_BCD: cols 1024..1071 (B,C,delta) + scan-input transforms. BM=128, 48 cols ----
__global__ __launch_bounds__(256, 2) void gemm_bcd_kernel(
    const short* __restrict__ xbp, const short* __restrict__ Wt1p,
    const float* __restrict__ b_in, const float* __restrict__ A_log,
    float* __restrict__ Bb, float* __restrict__ Cb, float* __restrict__ ab) {
  __shared__ short Ash[3 * 4096] __attribute__((aligned(16)));
  __shared__ short Bsh[3 * 2048] __attribute__((aligned(16)));
  const int tid = threadIdx.x;
  const int lane = tid & 63, wave = tid >> 6;
  const int l15 = lane & 15, ks = lane >> 4;
  const int bid = blockIdx.x;                   // 0..511
  const int mt = (bid & 7) * 64 + (bid >> 3);
  const short* Abase = xbp + (long)mt * TSTRIDE;
  const short* Bbase = Wt1p + (long)8 * TSTRIDE;  // panel 8 = cols 1024..1151

  fx4 acc[2][3];
#pragma unroll
  for (int i = 0; i < 2; i++)
#pragma unroll
    for (int j = 0; j < 3; j++) acc[i][j] = fx4{0.f, 0.f, 0.f, 0.f};

  const int rslot = ((ks + (l15 >> 1)) & 3) * 8;
  const int aofb = (wave * 32 + l15) * 32 + rslot;

#pragma unroll
  for (int s = 0; s < 2; s++) {
    GLOAD_LDS16(Abase + (long)s * TILE_SHORTS + tid * 8, Ash + s * 4096 + tid * 8);
    GLOAD_LDS16(Abase + (long)s * TILE_SHORTS + 2048 + tid * 8, Ash + s * 4096 + 2048 + tid * 8);
    GLOAD_LDS16(Bbase + (long)s * TILE_SHORTS + tid * 8, Bsh + s * 2048 + tid * 8);
  }

  for (int s = 0; s < NSTEP; ++s) {
    if (s < NSTEP - 1) asm volatile("s_waitcnt vmcnt(3)" ::: "memory");
    else               asm volatile("s_waitcnt vmcnt(0)" ::: "memory");
    SBAR();
    if (s + 2 < NSTEP) {
      const int sl = (s + 2) % 3;
      GLOAD_LDS16(Abase + (long)(s + 2) * TILE_SHORTS + tid * 8, Ash + sl * 4096 + tid * 8);
      GLOAD_LDS16(Abase + (long)(s + 2) * TILE_SHORTS + 2048 + tid * 8, Ash + sl * 4096 + 2048 + tid * 8);
      GLOAD_LDS16(Bbase + (long)(s + 2) * TILE_SHORTS + tid * 8, Bsh + sl * 2048 + tid * 8);
    }
    const short* sa = Ash + (s % 3) * 4096 + aofb;
    const short* sb = Bsh + (s % 3) * 2048;
    sx8 af[2], bfr[3];
#pragma unroll
    for (int i = 0; i < 2; i++) af[i] = *(const sx8*)(sa + i * 512);
#pragma unroll
    for (int j = 0; j < 3; j++) bfr[j] = *(const sx8*)(sb + (j * 16 + l15) * 32 + rslot);
#pragma unroll
    for (int i = 0; i < 2; i++)
#pragma unroll
      for (int j = 0; j < 3; j++)
        acc[i][j] = __builtin_amdgcn_mfma_f32_16x16x32_bf16(af[i], bfr[j], acc[i][j], 0, 0, 0);
  }

  const float biasB = b_in[2048 + l15];
  const float biasC = b_in[2064 + l15];
  const float biasD = b_in[2080 + l15];
  const float Ac = -expf(A_log[l15]);
#pragma unroll
  for (int mi = 0; mi < 2; mi++) {
#pragma unroll
    for (int r = 0; r < 4; r++) {
      int m = mt * 128 + wave * 32 + mi * 16 + (lane >> 4) * 4 + r;
      Bb[m * NSTATE + l15] = acc[mi][0][r] + biasB;
      Cb[m * NSTATE + l15] = acc[mi][1][r] + biasC;
      float v = acc[mi][2][r] + biasD;
      float dlt = (v > 20.f) ? v : log1pf(expf(v));
      ab[m * NSTATE + l15] = expf(Ac * dlt);
    }
  }
}

// ---- segmented selective scan + fused channel-reduce: 1 block/batch, 256 thr ----
__global__ void scan_kernel(const float* __restrict__ ab, const float* __restrict__ Bb,
                            const float* __restrict__ Cb, float* __restrict__ y) {
  __shared__ float Ash[16][17], Bsh[16][17];
  const int b = blockIdx.x;
  const int tid = threadIdx.x;
  const int seg = tid >> 4, ch = tid & 15;
  const long base = ((long)b * SEQ_LEN + seg * 128) * NSTATE + ch;
  const float* pa = ab + base;
  const float* pb = Bb + base;
  const float* pc = Cb + base;

  // pass 1: segment composition
  float A = 1.f, Bc = 0.f;
  for (int i0 = 0; i0 < 128; i0 += 8) {
    float av[8], bv[8];
#pragma unroll
    for (int u = 0; u < 8; u++) { av[u] = pa[(i0 + u) * NSTATE]; bv[u] = pb[(i0 + u) * NSTATE]; }
#pragma unroll
    for (int u = 0; u < 8; u++) { Bc = fmaf(av[u], Bc, bv[u]); A *= av[u]; }
  }
  Ash[seg][ch] = A; Bsh[seg][ch] = Bc;
  __syncthreads();

  // exclusive prefix over segments, per channel
  if (tid < 16) {
    float s = 0.f;
    for (int sg = 0; sg < 16; ++sg) {
      float nxt = fmaf(Ash[sg][tid], s, Bsh[sg][tid]);
      Bsh[sg][tid] = s;          // state ENTERING segment sg
      s = nxt;
    }
  }
  __syncthreads();

  // pass 2: apply + 16-lane reduce -> y
  float s = Bsh[seg][ch];
  float* py = y + (long)b * SEQ_LEN + seg * 128;
  for (int i0 = 0; i0 < 128; i0 += 8) {
    float av[8], bv[8], cv[8];
#pragma unroll
    for (int u = 0; u < 8; u++) {
      av[u] = pa[(i0 + u) * NSTATE];
      bv[u] = pb[(i0 + u) * NSTATE];
      cv[u] = pc[(i0 + u) * NSTATE];
    }
#pragma unroll
    for (int u = 0; u < 8; u++) {
      s = fmaf(av[u], s, bv[u]);
      float p = s * cv[u];
      p += __shfl_xor(p, 1);
      p += __shfl_xor(p, 2);
      p += __shfl_xor(p, 4);
      p += __shfl_xor(p, 8);
      if (ch == 0) py[i0 + u] = p;
    }
  }
}

// ---------------- GEMM2: out = (y ⊙row g) @ W_out + b_out ----------------
__global__ __launch_bounds__(1024, 1) void gemm2_kernel(
    const short* __restrict__ g, const short* __restrict__ Wt2p,
    const float* __restrict__ y, const float* __restrict__ b_out,
    float* __restrict__ out) {
  extern __shared__ short lds[];
  const int bid = blockIdx.x;                 // 0..1023
  const int wgid = (bid & 7) * 128 + (bid >> 3);
  const int nt = wgid & 3;
  const int mt = wgid >> 2;                   // 0..255
  fx4 acc[4][4];
  gemm_mainloop256(g + (long)(mt * 2) * TSTRIDE,
                   Wt2p + (long)(nt * 2) * TSTRIDE, lds, acc);

  const int lane = threadIdx.x & 63;
  const int wave = threadIdx.x >> 6;
  const int wm = wave >> 2, wn = wave & 3;
  const int m0 = mt * 256;
  const int n0 = nt * 256;

#pragma unroll
  for (int mi = 0; mi < 4; mi++) {
#pragma unroll
    for (int r = 0; r < 4; r++) {
      int m = m0 + wm * 64 + mi * 16 + (lane >> 4) * 4 + r;
      float ym = y[m];
#pragma unroll
      for (int ni = 0; ni < 4; ni++) {
        int n = n0 + wn * 64 + ni * 16 + (lane & 15);
        out[(long)m * 1024 + n] = fmaf(ym, acc[mi][ni][r], b_out[n]);
      }
    }
  }
}

extern "C" void kernel_launch(void* const* d_in, const int* in_sizes, int n_in,
                              void* d_out, int out_size, void* d_ws, size_t ws_size,
                              hipStream_t stream) {
  const float* x     = (const float*)d_in[0];
  const float* W_in  = (const float*)d_in[1];
  const float* b_in  = (const float*)d_in[2];
  const float* A_log = (const float*)d_in[3];
  const float* W_out = (const float*)d_in[4];
  const float* b_out = (const float*)d_in[5];
  float* out = (float*)d_out;

  char* ws = (char*)d_ws;
  short* xbp = (short*)ws;  ws += (size_t)MROWS * KDIM * 2;      // 134.2 MB packed
  short* g   = (short*)ws;  ws += (size_t)MROWS * KDIM * 2;      // 134.2 MB packed
  short* Wt1p = (short*)ws; ws += (size_t)N1PAD * KDIM * 2;      // 2.36 MB packed
  short* Wt2p = (short*)ws; ws += (size_t)KDIM * KDIM * 2;       // 2.10 MB packed
  float* Bb = (float*)ws;  ws += (size_t)MROWS * NSTATE * 4;     // 4.19 MB
  float* Cb = (float*)ws;  ws += (size_t)MROWS * NSTATE * 4;
  float* ab = (float*)ws;  ws += (size_t)MROWS * NSTATE * 4;
  float* y  = (float*)ws;  ws += (size_t)MROWS * 4;

  const int ldsBytes = 2 * RING * SLOT_SHORTS * 2;   // 128 KB

  convert_pack_x<<<4096, 256, 0, stream>>>(x, xbp);
  transpose_w_kernel<<<dim3(N1PAD / 32, 32), 256, 0, stream>>>(W_in, Wt1p, 2096, 1024, N1);
  transpose_w_kernel<<<dim3(32, 32), 256, 0, stream>>>(W_out, Wt2p, 1024, 0, 1024);
  gemm_bcd_kernel<<<512, 256, 0, stream>>>(xbp, Wt1p, b_in, A_log, Bb, Cb, ab);
  scan_kernel<<<NBATCH, 256, 0, stream>>>(ab, Bb, Cb, y);
  gemm1_kernel<<<1024, 1024, ldsBytes, stream>>>(xbp, Wt1p, b_in, g);
  gemm2_kernel<<<1024, 1024, ldsBytes, stream>>>(g, Wt2p, y, b_out, out);
}